// Round 1
// 274.224 us; speedup vs baseline: 1.0427x; 1.0427x over previous
//
#include <hip/hip_runtime.h>

#define DI __device__ __forceinline__

typedef float  f32x2  __attribute__((ext_vector_type(2)));
typedef float  f32x4  __attribute__((ext_vector_type(4)));
typedef float  f32x16 __attribute__((ext_vector_type(16)));
typedef __bf16 bf16x8 __attribute__((ext_vector_type(8)));
typedef unsigned u32x2 __attribute__((ext_vector_type(2)));
typedef unsigned u32x4 __attribute__((ext_vector_type(4)));

static constexpr int TB   = 2048;   // tokens per batch
static constexpr int NTOK = 8192;   // 4 * 2048
static constexpr int EMB  = 1024;
static constexpr int FQKV = 3072;

// RTNE float -> bf16 bits
DI unsigned short f2bf(float f) {
  union { float f; unsigned u; } v; v.f = f;
  unsigned r = v.u + 0x7FFFu + ((v.u >> 16) & 1u);
  return (unsigned short)(r >> 16);
}

// pack two f32 -> two bf16 in one dword: low16 = a, high16 = b
DI unsigned pack2bf(float a, float b) {
#if __has_builtin(__builtin_amdgcn_cvt_pk_bf16_f32)
  typedef __bf16 bf16x2 __attribute__((ext_vector_type(2)));
  bf16x2 r = __builtin_amdgcn_cvt_pk_bf16_f32(a, b);
  return __builtin_bit_cast(unsigned, r);
#else
  unsigned ua = __builtin_bit_cast(unsigned, a) + 0x8000u;  // round-half-up
  unsigned ub = __builtin_bit_cast(unsigned, b) + 0x8000u;
  return __builtin_amdgcn_perm(ub, ua, 0x07060302u);
#endif
}

// v_permlane32_swap: a' = [a.lo32lanes, b.lo32lanes], b' = [a.hi32lanes, b.hi32lanes]
DI void plswap(unsigned& a, unsigned& b) {
#if __has_builtin(__builtin_amdgcn_permlane32_swap)
  u32x2 r = __builtin_amdgcn_permlane32_swap(a, b, false, false);
  a = r.x; b = r.y;
#else
  const bool hi = (threadIdx.x & 32) != 0;
  unsigned ax = (unsigned)__shfl_xor((int)a, 32);
  unsigned bx = (unsigned)__shfl_xor((int)b, 32);
  unsigned na = hi ? bx : a;
  unsigned nb = hi ? b : ax;
  a = na; b = nb;
#endif
}

DI bf16x8 frag4(unsigned a, unsigned b, unsigned c, unsigned d) {
  u32x4 u = {a, b, c, d};
  return __builtin_bit_cast(bf16x8, u);
}

// async global->LDS, 16B per lane; LDS dest = wave-uniform base + lane*16
DI void gload16(const void* g, void* l) {
  __builtin_amdgcn_global_load_lds(
      (__attribute__((address_space(1))) void*)(g),
      (__attribute__((address_space(3))) void*)(l), 16, 0, 0);
}

// barrier with GUARANTEED pre-drain of this wave's outstanding DMA/LDS ops.
// global_load_lds data is only visible to OTHER waves' ds_reads if the issuing
// wave drains vmcnt BEFORE s_barrier; compiler may legally defer that wait.
DI void syncdrain() {
  __builtin_amdgcn_s_waitcnt(0);
  __syncthreads();
}

// ---------------- fp32 -> bf16 conversion for x, w_qkv, w_out ----------------
__global__ __launch_bounds__(256)
void cvt_kernel(const float4* __restrict__ x, const float4* __restrict__ wq,
                const float4* __restrict__ wo,
                ushort4* __restrict__ xb, ushort4* __restrict__ wqb,
                ushort4* __restrict__ wob) {
  const int i  = blockIdx.x * 256 + threadIdx.x;
  const int nx = NTOK * EMB / 4;       // 2097152
  const int nq = FQKV * EMB / 4;       // 786432
  float4 v; ushort4* dst;
  if (i < nx)           { v = x[i];           dst = xb  + i; }
  else if (i < nx + nq) { v = wq[i - nx];     dst = wqb + (i - nx); }
  else                  { v = wo[i - nx - nq]; dst = wob + (i - nx - nq); }
  ushort4 p;
  p.x = f2bf(v.x); p.y = f2bf(v.y); p.z = f2bf(v.z); p.w = f2bf(v.w);
  *dst = p;
}

// ---------------- 128x128 bf16 GEMM, C = A * Bt^T (both row-major [.,K]) ----
template <int MODE>
__global__ __launch_bounds__(256)
void gemm_bt(const unsigned short* __restrict__ A,
             const unsigned short* __restrict__ Bt,
             const int K,
             unsigned short* __restrict__ qk,
             unsigned short* __restrict__ vT,
             float* __restrict__ outp) {
  __shared__ unsigned short sA[128 * 32];
  __shared__ unsigned short sB[128 * 32];
  const int tid  = threadIdx.x;
  const int w    = tid >> 6;
  const int l    = tid & 63;
  const int quad = l >> 4;
  const int lr   = l & 15;
  const int n0   = blockIdx.x * 128;
  const int m0   = blockIdx.y * 128;
  const int wm   = (w >> 1) * 64;
  const int wn   = (w & 1) * 64;

  f32x4 acc[4][4];
#pragma unroll
  for (int i = 0; i < 4; ++i)
#pragma unroll
    for (int j = 0; j < 4; ++j) acc[i][j] = {0.f, 0.f, 0.f, 0.f};

  const int srow = l >> 2;
  const int sg   = (l & 3) ^ ((l >> 3) & 3);
  const unsigned short* gA = A  + (long)(m0 + w * 32 + srow) * K + sg * 8;
  const unsigned short* gB = Bt + (long)(n0 + w * 32 + srow) * K + sg * 8;
  unsigned short* lA = sA + w * 1024;
  unsigned short* lB = sB + w * 1024;
  const int swz = (lr >> 1) & 3;

  for (int k0 = 0; k0 < K; k0 += 32) {
    gload16(gA + k0,          lA);
    gload16(gA + k0 + 16 * K, lA + 512);
    gload16(gB + k0,          lB);
    gload16(gB + k0 + 16 * K, lB + 512);
    syncdrain();
    bf16x8 af[4], bfr[4];
#pragma unroll
    for (int rt = 0; rt < 4; ++rt)
      af[rt] = *(const bf16x8*)(sA + (wm + rt * 16 + lr) * 32 + (quad ^ swz) * 8);
#pragma unroll
    for (int ct = 0; ct < 4; ++ct)
      bfr[ct] = *(const bf16x8*)(sB + (wn + ct * 16 + lr) * 32 + (quad ^ swz) * 8);
#pragma unroll
    for (int rt = 0; rt < 4; ++rt)
#pragma unroll
      for (int ct = 0; ct < 4; ++ct)
        acc[rt][ct] = __builtin_amdgcn_mfma_f32_16x16x32_bf16(af[rt], bfr[ct],
                                                              acc[rt][ct], 0, 0, 0);
    __syncthreads();
  }

  if (MODE == 0) {
    if (n0 < 2048) {
      const float qs = (n0 < 1024) ? 0.18033688011112042f : 1.0f;
#pragma unroll
      for (int rt = 0; rt < 4; ++rt) {
        const int row = m0 + wm + rt * 16 + quad * 4;
#pragma unroll
        for (int ct = 0; ct < 4; ++ct) {
          const int col = n0 + wn + ct * 16 + lr;
#pragma unroll
          for (int r = 0; r < 4; ++r)
            qk[(long)(row + r) * 2048 + col] = f2bf(acc[rt][ct][r] * qs);
        }
      }
    } else {
#pragma unroll
      for (int rt = 0; rt < 4; ++rt) {
        const int tok = m0 + wm + rt * 16 + quad * 4;
        const int bb  = tok >> 11, tt = tok & 2047;
#pragma unroll
        for (int ct = 0; ct < 4; ++ct) {
          const int fv = n0 - 2048 + wn + ct * 16 + lr;  // h*64+d
          ushort4 p;
          p.x = f2bf(acc[rt][ct][0]); p.y = f2bf(acc[rt][ct][1]);
          p.z = f2bf(acc[rt][ct][2]); p.w = f2bf(acc[rt][ct][3]);
          *(ushort4*)(vT + ((long)(bb * 1024 + fv)) * 2048 + tt) = p;
        }
      }
    }
  } else {
#pragma unroll
    for (int rt = 0; rt < 4; ++rt) {
      const int row = m0 + wm + rt * 16 + quad * 4;
#pragma unroll
      for (int ct = 0; ct < 4; ++ct) {
        const int col = n0 + wn + ct * 16 + lr;
#pragma unroll
        for (int r = 0; r < 4; ++r)
          outp[(long)(row + r) * 1024 + col] = acc[rt][ct][r];
      }
    }
  }
}

// ---------------- flash attention v6: occupancy doubled ----------------------
// r0 theory: v5 had 2048 waves total (2/SIMD) -> softmax VALU, MFMA, and LDS
// phases of one wave can't overlap anything (MfmaUtil 28 + VALUBusy 53, occ 18%).
// v6: each wave owns ONE 32-q set (was two) -> block = 128 q, grid (64 bh, 16 qt)
// = 4096 waves = 4 blocks/CU (LDS 128KB) = 4 waves/SIMD. Per-wave state halves
// (oacc 32 + qf 16 + sacc 16 regs) so __launch_bounds__(256,4) (<=128 regs) fits.
// Cost: per-CU LDS read traffic doubles (K/V frags no longer amortized over 2
// q-sets) -- budgeted ~98K cyc/CU, still under runtime. T5 setprio added around
// MFMA clusters (measured +4-7% on attn once waves have role diversity).
__global__ __launch_bounds__(256, 4)
void attn_kernel(const unsigned short* __restrict__ qk,
                 const unsigned short* __restrict__ vT,
                 unsigned short* __restrict__ attnb) {
  __shared__ unsigned short sK[2][64 * 64];  // [key][d], 16B-granule swizzled
  __shared__ unsigned short sV[2][64 * 64];  // [d][t],  16B-granule swizzled
  const int tid = threadIdx.x;
  const int w   = tid >> 6;
  const int l   = tid & 63;
  const int l31 = l & 31;
  const int lh  = l >> 5;            // lane half
  const int h8  = lh * 8;            // k-offset of this lane-half in A/B frags
  const int bh  = blockIdx.x;
  const int hh  = bh & 15;
  const long tokbase = (long)(bh >> 4) * TB;
  const int qbase = blockIdx.y * 128 + w * 32;   // this wave's 32-q set

  // Q fragments (B operand): Q[q = l31][d = s*16 + h8 + j]
  bf16x8 qf[4];
  {
    const unsigned short* qptr = qk + (tokbase + qbase + l31) * 2048 + hh * 64 + h8;
#pragma unroll
    for (int s = 0; s < 4; ++s) qf[s] = *(const bf16x8*)(qptr + s * 16);
  }

  // staging geometry (verified r3): instr covers 8 rows x 8 granules (16B);
  // LDS position spos of row r holds global granule spos ^ (r&7).
  const int srow = l >> 3;
  const int g    = (l & 7) ^ srow;
  const unsigned short* kbase =
      qk + (tokbase + w * 16 + srow) * 2048 + 1024 + hh * 64 + g * 8;
  const unsigned short* vbase =
      vT + ((long)bh * 64 + w * 16 + srow) * 2048 + g * 8;

  f32x16 oacc[2] = {{}, {}};
  f32x2 lp2 = {0.f, 0.f};

  // stage tile 0 into buf 0
  gload16(kbase,            &sK[0][(w * 16 + 0) * 64]);
  gload16(kbase + 8 * 2048, &sK[0][(w * 16 + 8) * 64]);
  gload16(vbase,            &sV[0][(w * 16 + 0) * 64]);
  gload16(vbase + 8 * 2048, &sV[0][(w * 16 + 8) * 64]);
  syncdrain();

  for (int t = 0; t < 32; ++t) {
    const int buf = t & 1;
    if (t + 1 < 32) {
      const int k0 = (t + 1) * 64;
      const int nb = buf ^ 1;
      gload16(kbase + (long)k0 * 2048,            &sK[nb][(w * 16 + 0) * 64]);
      gload16(kbase + (long)k0 * 2048 + 8 * 2048, &sK[nb][(w * 16 + 8) * 64]);
      gload16(vbase + k0,                         &sV[nb][(w * 16 + 0) * 64]);
      gload16(vbase + k0 + 8 * 2048,              &sV[nb][(w * 16 + 8) * 64]);
    }
    const unsigned short* bK = sK[buf];
    const unsigned short* bV = sV[buf];

#pragma unroll
    for (int G = 0; G < 2; ++G) {
      // S^T: A = K rows (32 keys), B = Q frags
      f32x16 sacc = {};
      __builtin_amdgcn_s_setprio(1);
#pragma unroll
      for (int s = 0; s < 4; ++s) {
        const int key = G * 32 + l31;
        const int p   = (s * 2 + lh) ^ (key & 7);
        const bf16x8 kf = *(const bf16x8*)(bK + key * 64 + p * 8);
        sacc = __builtin_amdgcn_mfma_f32_32x32x16_bf16(kf, qf[s], sacc, 0, 0, 0);
      }
      __builtin_amdgcn_s_setprio(0);
      // softmax numerators + repack to A-frag key order
      float e[16];
#pragma unroll
      for (int i = 0; i < 16; ++i) e[i] = __builtin_amdgcn_exp2f(sacc[i]);
#pragma unroll
      for (int i = 0; i < 8; ++i) {
        f32x2 pr = {e[2 * i], e[2 * i + 1]};
        lp2 += pr;                      // v_pk_add_f32
      }
      unsigned d[8];
#pragma unroll
      for (int i = 0; i < 8; ++i) d[i] = pack2bf(e[2 * i], e[2 * i + 1]);
      plswap(d[0], d[2]); plswap(d[1], d[3]);
      plswap(d[4], d[6]); plswap(d[5], d[7]);
      bf16x8 pp[2];
      pp[0] = frag4(d[0], d[1], d[2], d[3]);
      pp[1] = frag4(d[4], d[5], d[6], d[7]);
      // O += P V
      __builtin_amdgcn_s_setprio(1);
#pragma unroll
      for (int sub = 0; sub < 2; ++sub) {
        const int gt  = (G * 2 + sub) * 2 + lh;
        const int d0r = l31, d1r = 32 + l31;
        const bf16x8 vf0 = *(const bf16x8*)(bV + d0r * 64 + ((gt ^ (d0r & 7))) * 8);
        const bf16x8 vf1 = *(const bf16x8*)(bV + d1r * 64 + ((gt ^ (d1r & 7))) * 8);
        oacc[0] = __builtin_amdgcn_mfma_f32_32x32x16_bf16(pp[sub], vf0, oacc[0], 0, 0, 0);
        oacc[1] = __builtin_amdgcn_mfma_f32_32x32x16_bf16(pp[sub], vf1, oacc[1], 0, 0, 0);
      }
      __builtin_amdgcn_s_setprio(0);
    }
    syncdrain();
  }

  // normalize: each lane's lp covers half the keys for q = lane&31
  const float lp = lp2.x + lp2.y;
  const float fs = lp + __shfl_xor(lp, 32);
  const float rc = 1.0f / fs;
#pragma unroll
  for (int r = 0; r < 16; ++r) {
    const int row = (r & 3) + 8 * (r >> 2) + 4 * lh;  // q within 32-q set
    const float sc = __shfl(rc, row);
    const long base = (tokbase + qbase + row) * 1024 + hh * 64;
    attnb[base + l31]      = f2bf(oacc[0][r] * sc);
    attnb[base + 32 + l31] = f2bf(oacc[1][r] * sc);
  }
}

// ---------------------------------------------------------------------------
extern "C" void kernel_launch(void* const* d_in, const int* in_sizes, int n_in,
                              void* d_out, int out_size, void* d_ws, size_t ws_size,
                              hipStream_t stream) {
  const float* x    = (const float*)d_in[0];
  const float* wqkv = (const float*)d_in[1];
  const float* wout = (const float*)d_in[2];
  float* outp = (float*)d_out;

  unsigned short* xb    = (unsigned short*)d_ws;          // 8192*1024
  unsigned short* wqkvb = xb    + (long)NTOK * EMB;       // 3072*1024
  unsigned short* woutb = wqkvb + (long)FQKV * EMB;       // 1024*1024
  unsigned short* qkb   = woutb + (long)EMB * EMB;        // 8192*2048 (Q|K)
  unsigned short* vTb   = qkb   + (long)NTOK * 2048;      // 4*16*64*2048
  unsigned short* attnb = vTb   + (long)4 * 16 * 64 * TB; // 8192*1024

  cvt_kernel<<<12288, 256, 0, stream>>>(
      (const float4*)x, (const float4*)wqkv, (const float4*)wout,
      (ushort4*)xb, (ushort4*)wqkvb, (ushort4*)woutb);

  gemm_bt<0><<<dim3(24, 64), 256, 0, stream>>>(xb, wqkvb, EMB, qkb, vTb, nullptr);

  // attention: grid (bh, qtile) -> XCD-local K/V reuse; 128 q per block,
  // 32 q per wave -> 4096 waves (4/SIMD) for VALU/MFMA/LDS cross-wave overlap
  attn_kernel<<<dim3(64, 16), 256, 0, stream>>>(qkb, vTb, attnb);

  gemm_bt<1><<<dim3(8, 64), 256, 0, stream>>>(attnb, woutb, EMB, nullptr, nullptr, outp);
}